// Round 6
// baseline (7258.552 us; speedup 1.0000x reference)
//
#include <hip/hip_runtime.h>
#include <hip/hip_bf16.h>
#include <stdint.h>

// Problem constants
#define NB 128    // batch
#define NT 512    // time steps
#define ND 256    // input dim
#define NH 1024   // hidden dim
#define NZ 128    // latent dim
#define NG 4096   // 4*NH gate width

typedef __attribute__((ext_vector_type(8))) __bf16 bf16x8;
typedef __attribute__((ext_vector_type(4))) __bf16 bf16x4;
typedef __attribute__((ext_vector_type(4))) float floatx4;

// Fast native transcendentals (v_exp_f32 / v_log_f32 / v_rcp_f32).
__device__ __forceinline__ float fsigmoid_(float x) {
  return __fdividef(1.0f, 1.0f + __expf(-x));
}
__device__ __forceinline__ float fsoftplus_(float x) {
  return fmaxf(x, 0.0f) + __logf(1.0f + __expf(-fabsf(x)));
}

// B-fragment loader: 8 fp32 rows (stride NG) -> bf16x8
__device__ __forceinline__ bf16x8 load_bfrag(const float* s) {
  bf16x8 v;
#pragma unroll
  for (int jj = 0; jj < 8; ++jj) v[jj] = (__bf16)s[jj * NG];
  return v;
}

// ---------------------------------------------------------------------------
// Kernel 1: convert x (B,T,D) fp32 -> xb (T,B,D) bf16
// ---------------------------------------------------------------------------
__global__ __launch_bounds__(256) void convert_x_kernel(
    const float4* __restrict__ x, __bf16* __restrict__ xb) {
  int i = blockIdx.x * 256 + threadIdx.x;
  int d4 = i & 63;
  int bt = i >> 6;
  int b = bt >> 9;
  int t = bt & 511;
  float4 v = x[i];
  bf16x4 o;
  o[0] = (__bf16)v.x; o[1] = (__bf16)v.y; o[2] = (__bf16)v.z; o[3] = (__bf16)v.w;
  *(bf16x4*)(xb + ((t * NB + b) * ND + d4 * 4)) = o;
}

// ---------------------------------------------------------------------------
// Kernel 2: persistent LSTM — R15: sentinel sync + dual-group pipelining.
// R13/R14's proven sentinel machinery, now with TWO independent recurrences
// per WG so each group's ~2-LLC-RT broadcast hides under the other group's
// compute half. (R10's dual-group failed only because its flag protocol's
// vmcnt(0) drains serialized the two round trips; sentinels have no flags
// and no drains — detection is data-borne.)
//
// Mapping: 16 m-groups of 8 batch rows. WG (pp=wg&7, n_blk=wg>>3) owns
// tiles (mA=pp, mB=pp+8), SAME h-cols [n_blk*32,+32) -> all 160 B-frag
// VGPRs shared. Clique(pp) = the 32 WGs {(pp, n)} serves BOTH groups:
// fan-in stays 32. MFMA A-rows 8..15 duplicate rows 0..7 (lane n16>=8
// loads row n16&7); duplicate outputs are discarded (MFMA is ~5% of the
// step — the waste is free). Each group: own c-state, own accumulator set
// (AA/AB), own Gs slice, own rows of the SAME 4-deep ring (disjoint rows
// -> single-writer per word preserved; R13 re-arm safety unchanged).
//
// KEY INVARIANT (unchanged): h >= 0 -> published bf16 sign bit 0; sentinel
// 0xFFFF has sign set. Lazy poll: reload only words still sentinel.
// Per iteration: [A half: poll/gather hA(t) -> 32 hMFMA -> reduce Gs[0] ->
// barrier -> cell(tid<256) -> publish hA(t+1) + re-sentinel -> XPHASE_A]
// then the same for B. While A's publish round-trips, the B half computes;
// A(t+1) is polled one full B-half after it was published -> RT hidden.
// Gs single-buffered PER GROUP: cell(G) reads sit between the G-barrier
// and the other group's barrier; the next writes to Gs[G] come after that
// other barrier -> race-free by barrier separation.
// ---------------------------------------------------------------------------
__global__ __launch_bounds__(512, 1) void lstm_persistent(
    const __bf16* __restrict__ xb,    // (T, B, D) bf16
    const float* __restrict__ W,      // (D, 4H)
    const float* __restrict__ U,      // (H, 4H)
    const float* __restrict__ bias,   // (4H)
    __bf16* __restrict__ hbuf,        // 4 * B * H bf16 (ring)
    float* __restrict__ hlast)        // B * H fp32
{
  const int tid = threadIdx.x;
  const int wg = blockIdx.x;
  const int pp = wg & 7;
  const int n_blk = wg >> 3;           // 0..31
  const int mA = pp;
  const int mB = pp + 8;
  const int wave = tid >> 6;
  const int lane = tid & 63;
  const int q = lane >> 4;     // k-quad
  const int n16 = lane & 15;   // MFMA col within 16-col tile
  const int r8g = n16 & 7;     // gather row within 8-row group (dup n16>=8)

  __shared__ float Gs[2][8][8][132];   // [group][wave][row0..7][128+4 pad]

#define AL(p) __hip_atomic_load(p, __ATOMIC_RELAXED, __HIP_MEMORY_SCOPE_AGENT)
#define AS(p, v) __hip_atomic_store(p, v, __ATOMIC_RELAXED, __HIP_MEMORY_SCOPE_AGENT)
#define MFMA_(a, b, acc) __builtin_amdgcn_mfma_f32_16x16x32_bf16(a, b, acc, 0, 0, 0)

  // ---- Gate-column bases (4 gates x 2 col-halves) ----
  const int nb = n_blk * 32 + n16;
  const int c00 = nb,            c01 = nb + 16;
  const int c10 = NH + nb,       c11 = NH + nb + 16;
  const int c20 = 2 * NH + nb,   c21 = 2 * NH + nb + 16;
  const int c30 = 3 * NH + nb,   c31 = 3 * NH + nb + 16;

  // ---- Persistent B fragments (shared by both groups) ----
  const float* Wb = W + (wave * 32 + q * 8) * NG;
  bf16x8 BX00 = load_bfrag(Wb + c00), BX01 = load_bfrag(Wb + c01);
  bf16x8 BX10 = load_bfrag(Wb + c10), BX11 = load_bfrag(Wb + c11);
  bf16x8 BX20 = load_bfrag(Wb + c20), BX21 = load_bfrag(Wb + c21);
  bf16x8 BX30 = load_bfrag(Wb + c30), BX31 = load_bfrag(Wb + c31);
  const float* Ub = U + (wave * 128 + q * 8) * NG;
#define DECL_J(J)                                                       \
  bf16x8 BH00##J = load_bfrag(Ub + (J) * 32 * NG + c00);                \
  bf16x8 BH01##J = load_bfrag(Ub + (J) * 32 * NG + c01);                \
  bf16x8 BH10##J = load_bfrag(Ub + (J) * 32 * NG + c10);                \
  bf16x8 BH11##J = load_bfrag(Ub + (J) * 32 * NG + c11);                \
  bf16x8 BH20##J = load_bfrag(Ub + (J) * 32 * NG + c20);                \
  bf16x8 BH21##J = load_bfrag(Ub + (J) * 32 * NG + c21);                \
  bf16x8 BH30##J = load_bfrag(Ub + (J) * 32 * NG + c30);                \
  bf16x8 BH31##J = load_bfrag(Ub + (J) * 32 * NG + c31);
  DECL_J(0) DECL_J(1) DECL_J(2) DECL_J(3)
#undef DECL_J

  // Bias folded into wave 0's accumulator init only (partials are summed)
  const float b00 = (wave == 0) ? bias[c00] : 0.f;
  const float b01 = (wave == 0) ? bias[c01] : 0.f;
  const float b10 = (wave == 0) ? bias[c10] : 0.f;
  const float b11 = (wave == 0) ? bias[c11] : 0.f;
  const float b20 = (wave == 0) ? bias[c20] : 0.f;
  const float b21 = (wave == 0) ? bias[c21] : 0.f;
  const float b30 = (wave == 0) ? bias[c30] : 0.f;
  const float b31 = (wave == 0) ? bias[c31] : 0.f;

  float csA = 0.0f, csB = 0.0f;        // per-group cell states (tid<256 use)

  // Two accumulator sets (A group / B group), both live across halves.
  floatx4 AA00, AA01, AA10, AA11, AA20, AA21, AA30, AA31;
  floatx4 AB00, AB01, AB10, AB11, AB20, AB21, AB30, AB31;

#define XPHASE_P(P, XA)                                                 \
  {                                                                     \
    P##00 = (floatx4){b00, b00, b00, b00}; P##01 = (floatx4){b01, b01, b01, b01}; \
    P##10 = (floatx4){b10, b10, b10, b10}; P##11 = (floatx4){b11, b11, b11, b11}; \
    P##20 = (floatx4){b20, b20, b20, b20}; P##21 = (floatx4){b21, b21, b21, b21}; \
    P##30 = (floatx4){b30, b30, b30, b30}; P##31 = (floatx4){b31, b31, b31, b31}; \
    P##00 = MFMA_(XA, BX00, P##00); P##01 = MFMA_(XA, BX01, P##01);     \
    P##10 = MFMA_(XA, BX10, P##10); P##11 = MFMA_(XA, BX11, P##11);     \
    P##20 = MFMA_(XA, BX20, P##20); P##21 = MFMA_(XA, BX21, P##21);     \
    P##30 = MFMA_(XA, BX30, P##30); P##31 = MFMA_(XA, BX31, P##31);     \
  }

#define HMFMA_P(P, a0, a1, a2, a3)                                      \
  {                                                                     \
    P##00 = MFMA_(a0, BH000, P##00); P##01 = MFMA_(a0, BH010, P##01);   \
    P##10 = MFMA_(a0, BH100, P##10); P##11 = MFMA_(a0, BH110, P##11);   \
    P##20 = MFMA_(a0, BH200, P##20); P##21 = MFMA_(a0, BH210, P##21);   \
    P##30 = MFMA_(a0, BH300, P##30); P##31 = MFMA_(a0, BH310, P##31);   \
    P##00 = MFMA_(a1, BH001, P##00); P##01 = MFMA_(a1, BH011, P##01);   \
    P##10 = MFMA_(a1, BH101, P##10); P##11 = MFMA_(a1, BH111, P##11);   \
    P##20 = MFMA_(a1, BH201, P##20); P##21 = MFMA_(a1, BH211, P##21);   \
    P##30 = MFMA_(a1, BH301, P##30); P##31 = MFMA_(a1, BH311, P##31);   \
    P##00 = MFMA_(a2, BH002, P##00); P##01 = MFMA_(a2, BH012, P##01);   \
    P##10 = MFMA_(a2, BH102, P##10); P##11 = MFMA_(a2, BH112, P##11);   \
    P##20 = MFMA_(a2, BH202, P##20); P##21 = MFMA_(a2, BH212, P##21);   \
    P##30 = MFMA_(a2, BH302, P##30); P##31 = MFMA_(a2, BH312, P##31);   \
    P##00 = MFMA_(a3, BH003, P##00); P##01 = MFMA_(a3, BH013, P##01);   \
    P##10 = MFMA_(a3, BH103, P##10); P##11 = MFMA_(a3, BH113, P##11);   \
    P##20 = MFMA_(a3, BH203, P##20); P##21 = MFMA_(a3, BH213, P##21);   \
    P##30 = MFMA_(a3, BH303, P##30); P##31 = MFMA_(a3, BH313, P##31);   \
  }

  // x A-fragment address for step T, group MG (16B contiguous from xb)
#define XFRAG_PTR(T, MG)                                                \
  (const bf16x8*)(xb + ((T) * NB + (MG) * 8 + r8g) * ND + wave * 32 + q * 8)

  const unsigned long long SGN = 0x8000800080008000ULL;

  // One half-step for group MG (G = Gs slice, CS = cell state, P = acc set)
#define HALF(G, MG, CS, P)                                              \
  {                                                                     \
    bf16x8 xv;                                                          \
    if (t < NT - 1) xv = *XFRAG_PTR(t + 1, MG);                         \
    unsigned long long w0 = SGN, w1 = SGN, w2 = SGN, w3 = SGN,          \
                       w4 = SGN, w5 = SGN, w6 = SGN, w7 = SGN;          \
    {                                                                   \
      const unsigned long long* hp = (const unsigned long long*)        \
          (hbuf + (t & 3) * (NB * NH) + ((MG) * 8 + r8g) * NH           \
           + (wave << 7) + (q << 3));                                   \
      while (true) {                                                    \
        if (w0 & SGN) w0 = AL(hp);                                      \
        if (w1 & SGN) w1 = AL(hp + 1);                                  \
        if (w2 & SGN) w2 = AL(hp + 8);                                  \
        if (w3 & SGN) w3 = AL(hp + 9);                                  \
        if (w4 & SGN) w4 = AL(hp + 16);                                 \
        if (w5 & SGN) w5 = AL(hp + 17);                                 \
        if (w6 & SGN) w6 = AL(hp + 24);                                 \
        if (w7 & SGN) w7 = AL(hp + 25);                                 \
        unsigned long long s =                                          \
            (w0 | w1 | w2 | w3 | w4 | w5 | w6 | w7) & SGN;              \
        if (__all(s == 0ULL)) break;                                    \
        __builtin_amdgcn_s_sleep(1);                                    \
      }                                                                 \
    }                                                                   \
    union { unsigned long long u[2]; bf16x8 v; } u0, u1, u2, u3;        \
    u0.u[0] = w0; u0.u[1] = w1; u1.u[0] = w2; u1.u[1] = w3;             \
    u2.u[0] = w4; u2.u[1] = w5; u3.u[0] = w6; u3.u[1] = w7;             \
    bf16x8 a0 = u0.v, a1 = u1.v, a2 = u2.v, a3 = u3.v;                  \
    HMFMA_P(P, a0, a1, a2, a3)                                          \
    if (q < 2) {                                                        \
      _Pragma("unroll")                                                 \
      for (int rr = 0; rr < 4; ++rr) {                                  \
        int row = q * 4 + rr;                                           \
        Gs[G][wave][row][n16]       = P##00[rr];                        \
        Gs[G][wave][row][16 + n16]  = P##01[rr];                        \
        Gs[G][wave][row][32 + n16]  = P##10[rr];                        \
        Gs[G][wave][row][48 + n16]  = P##11[rr];                        \
        Gs[G][wave][row][64 + n16]  = P##20[rr];                        \
        Gs[G][wave][row][80 + n16]  = P##21[rr];                        \
        Gs[G][wave][row][96 + n16]  = P##30[rr];                        \
        Gs[G][wave][row][112 + n16] = P##31[rr];                        \
      }                                                                 \
    }                                                                   \
    __syncthreads();                                                    \
    if (tid < 256) {                                                    \
      const int r8 = tid >> 5;                                          \
      const int ce = tid & 31;                                          \
      const int growx = (MG) * 8 + r8;                                  \
      const int hc = n_blk * 32 + ce;                                   \
      float xi = 0.f, xf = 0.f, xg = 0.f, xo = 0.f;                     \
      _Pragma("unroll")                                                 \
      for (int w2i = 0; w2i < 8; ++w2i) {                               \
        xi += Gs[G][w2i][r8][ce];                                       \
        xf += Gs[G][w2i][r8][32 + ce];                                  \
        xg += Gs[G][w2i][r8][64 + ce];                                  \
        xo += Gs[G][w2i][r8][96 + ce];                                  \
      }                                                                 \
      float iv = fsigmoid_(xi);                                         \
      float fv = fsigmoid_(xf);                                         \
      float gv = fsoftplus_(xg);                                        \
      float ov = fsigmoid_(xo);                                         \
      (CS) = fv * (CS) + iv * gv;                                       \
      float hv = ov * fsoftplus_(CS);   /* hv >= 0: sign bit 0 */       \
      if (t == NT - 1) {                                                \
        hlast[growx * NH + hc] = hv;                                    \
      } else {                                                          \
        float hn1 = __shfl_xor(hv, 1);                                  \
        __hip_bfloat162 pk;                                             \
        pk.x = (__hip_bfloat16)hv; pk.y = (__hip_bfloat16)hn1;          \
        unsigned int pw = *(unsigned int*)&pk;                          \
        unsigned int po = (unsigned int)__shfl_xor((int)pw, 2);         \
        if ((ce & 3) == 0) {                                            \
          unsigned long long vv = ((unsigned long long)po << 32) | pw;  \
          AS((unsigned long long*)(hbuf + ((t + 1) & 3) * (NB * NH)     \
                                   + growx * NH + hc), vv);             \
          AS((unsigned long long*)(hbuf + ((t + 3) & 3) * (NB * NH)     \
                                   + growx * NH + hc),                  \
             0xFFFFFFFFFFFFFFFFULL);                                    \
        }                                                               \
      }                                                                 \
    }                                                                   \
    if (t < NT - 1) XPHASE_P(P, xv)                                     \
  }

  // ---- Prologue: x-phase for t=0, both groups ----
  {
    bf16x8 x0a = *XFRAG_PTR(0, mA);
    XPHASE_P(AA, x0a)
    bf16x8 x0b = *XFRAG_PTR(0, mB);
    XPHASE_P(AB, x0b)
  }

  for (int t = 0; t < NT; ++t) {
    HALF(0, mA, csA, AA)   // A's publish RT hides under the B half
    HALF(1, mB, csB, AB)   // B's publish RT hides under the next A half
  }
#undef HALF
#undef XFRAG_PTR
#undef HMFMA_P
#undef XPHASE_P
#undef AS
#undef AL
#undef MFMA_
}

// ---------------------------------------------------------------------------
// Kernel 3: projection head. 32 blocks x 128 thr; 4 batch rows per block.
// ---------------------------------------------------------------------------
__global__ __launch_bounds__(128) void proj_kernel(
    const float* __restrict__ hlast,
    const float* __restrict__ Wm, const float* __restrict__ bm,
    const float* __restrict__ Wv, const float* __restrict__ bv,
    const float* __restrict__ eps, float* __restrict__ out) {
  __shared__ float hs[4][NH];
  const int bb = blockIdx.x * 4;
  for (int idx = threadIdx.x; idx < 4 * NH; idx += 128)
    hs[idx >> 10][idx & (NH - 1)] = hlast[(bb + (idx >> 10)) * NH + (idx & (NH - 1))];
  __syncthreads();
  const int z = threadIdx.x;
  float am[4] = {0.f, 0.f, 0.f, 0.f};
  float av[4] = {0.f, 0.f, 0.f, 0.f};
#pragma unroll 8
  for (int k = 0; k < NH; ++k) {
    float wm = Wm[k * NZ + z];
    float wv = Wv[k * NZ + z];
#pragma unroll
    for (int r = 0; r < 4; ++r) {
      am[r] += hs[r][k] * wm;
      av[r] += hs[r][k] * wv;
    }
  }
#pragma unroll
  for (int r = 0; r < 4; ++r) {
    int b = bb + r;
    float mu = am[r] + bm[z];
    float lv = av[r] + bv[z];
    float zz = mu + eps[b * NZ + z] * expf(0.5f * lv);
    out[b * NZ + z] = mu;
    out[NB * NZ + b * NZ + z] = lv;
    out[2 * NB * NZ + b * NZ + z] = zz;
  }
}

// ---------------------------------------------------------------------------
extern "C" void kernel_launch(void* const* d_in, const int* in_sizes, int n_in,
                              void* d_out, int out_size, void* d_ws, size_t ws_size,
                              hipStream_t stream) {
  const float* x   = (const float*)d_in[0];
  const float* W   = (const float*)d_in[1];
  const float* U   = (const float*)d_in[2];
  const float* b   = (const float*)d_in[3];
  const float* Wm  = (const float*)d_in[4];
  const float* bm  = (const float*)d_in[5];
  const float* Wv  = (const float*)d_in[6];
  const float* bv  = (const float*)d_in[7];
  const float* eps = (const float*)d_in[8];

  // Workspace layout:
  //   [0,       1048576)   hbuf: 4-deep ring of B x H bf16 (256KB each)
  //   [1048576, +33.5MB)   xb: T x B x D bf16
  //   hlast (B x H fp32, 512KB) ALIASES xb's t<8 region: x(t<8) is dead
  //   after step 7; hlast is written only at step NT-1.
  char* ws = (char*)d_ws;
  __bf16* hbuf = (__bf16*)ws;
  __bf16* xb   = (__bf16*)(ws + 1048576);
  float* hlast = (float*)(ws + 1048576);

  // buf0 = h(0) = 0 (sign-clear = "present"); bufs 1..3 = 0xFFFF sentinel.
  hipMemsetAsync(hbuf, 0, NB * NH * sizeof(__bf16), stream);
  hipMemsetAsync(hbuf + NB * NH, 0xFF, 3 * NB * NH * sizeof(__bf16), stream);

  convert_x_kernel<<<dim3((NB * NT * ND) / 4 / 256), dim3(256), 0, stream>>>(
      (const float4*)x, xb);

  void* args[] = {(void*)&xb, (void*)&W, (void*)&U, (void*)&b,
                  (void*)&hbuf, (void*)&hlast};
  hipLaunchCooperativeKernel(reinterpret_cast<void*>(lstm_persistent),
                             dim3(256), dim3(512), args, 0, stream);

  proj_kernel<<<dim3(32), dim3(128), 0, stream>>>(hlast, Wm, bm, Wv, bv, eps,
                                                  (float*)d_out);
}

// Round 7
// 3344.278 us; speedup vs baseline: 2.1704x; 2.1704x over previous
//
#include <hip/hip_runtime.h>
#include <hip/hip_bf16.h>
#include <stdint.h>

// Problem constants
#define NB 128    // batch
#define NT 512    // time steps
#define ND 256    // input dim
#define NH 1024   // hidden dim
#define NZ 128    // latent dim
#define NG 4096   // 4*NH gate width

typedef __attribute__((ext_vector_type(8))) __bf16 bf16x8;
typedef __attribute__((ext_vector_type(4))) __bf16 bf16x4;
typedef __attribute__((ext_vector_type(4))) float floatx4;

// Fast native transcendentals (v_exp_f32 / v_log_f32 / v_rcp_f32).
__device__ __forceinline__ float fsigmoid_(float x) {
  return __fdividef(1.0f, 1.0f + __expf(-x));
}
__device__ __forceinline__ float fsoftplus_(float x) {
  return fmaxf(x, 0.0f) + __logf(1.0f + __expf(-fabsf(x)));
}

// B-fragment loader: 8 fp32 rows (stride NG) -> bf16x8
__device__ __forceinline__ bf16x8 load_bfrag(const float* s) {
  bf16x8 v;
#pragma unroll
  for (int jj = 0; jj < 8; ++jj) v[jj] = (__bf16)s[jj * NG];
  return v;
}

// ---------------------------------------------------------------------------
// Kernel 1: convert x (B,T,D) fp32 -> xb (T,B,D) bf16
// ---------------------------------------------------------------------------
__global__ __launch_bounds__(256) void convert_x_kernel(
    const float4* __restrict__ x, __bf16* __restrict__ xb) {
  int i = blockIdx.x * 256 + threadIdx.x;
  int d4 = i & 63;
  int bt = i >> 6;
  int b = bt >> 9;
  int t = bt & 511;
  float4 v = x[i];
  bf16x4 o;
  o[0] = (__bf16)v.x; o[1] = (__bf16)v.y; o[2] = (__bf16)v.z; o[3] = (__bf16)v.w;
  *(bf16x4*)(xb + ((t * NB + b) * ND + d4 * 4)) = o;
}

// ---------------------------------------------------------------------------
// Kernel 2: persistent LSTM — R16: sentinel sync + PIPELINED polling.
// R14 structure verbatim (R15's dual-group reverted). One change: the
// consumer's poll sampling discipline.
//
// Grid 256 WGs x 512 thr (1 WG/CU, m_blk = wg&7, n_blk = wg>>3). Clique for
// batch-group m = the 32 WGs {wg : wg&7==m}; each WG publishes a 16x32 h
// patch and gathers the full 16x1024 h row-block each step.
//
// KEY INVARIANT: h = sigmoid(o)*softplus(c) >= 0, so every published bf16
// has SIGN BIT 0. hbuf is a 4-deep ring; unwritten/retired buffers hold
// 0xFFFF (sign set). Consumers poll THE GATHER WORDS THEMSELVES:
// (w & 0x8000'8000'8000'8000) == 0 <=> that 8B word is fresh h. Each 8B
// word is single-writer-atomic and single-assignment per ring slot per
// step, so ANY sign-clear sample is the final value.
//
// R16 poll discipline:
//  (a) PRE-ISSUE: generation-A loads for step t+1 are issued at the END of
//      step t (after publish, before XPHASE) — the first sample is in
//      flight while XPHASE and loop overhead run.
//  (b) PING-PONG: the poll loop keeps TWO generations outstanding (A/B),
//      merging per-word (keep first sign-clear sample). Sample spacing
//      drops from ~1 LLC RT (R14: wait-all + sleep + reissue) to ~RT/2.
//      No s_sleep. R14 proved poll BW is not a limiter.
//
// Re-arm protocol unchanged (single-writer per word; WG (m,n) owns its
// patch in every buffer): at step t, after detecting full h(t),
// re-sentinel own patch of buf (t+3)&3 (held h(t-1), dead because full
// h(t) implies every clique member gathered h(t-1)). Durability: the
// __syncthreads vmcnt drain orders re-arm stores before the next publish.
// Pre-issued polls of buf (t+1)&3 are safe: they happen only after this
// WG detected full h(t), which implies every peer's re-arm of buf (t+1)&3
// already reached the LLC (peer re-armed it at step t-2, drained at its
// t-1 barrier, before publishing h(t)).
//
// Loop: [merge pre-issued A / ping-pong poll h(t)] -> 32 h-MFMAs ->
// reduce Gs[t&1] -> __syncthreads (ONLY barrier) -> cell -> publish
// h(t+1) -> re-sentinel -> pre-issue A for t+1 -> XPHASE(t+1).
// All comms = agent-scope relaxed atomics; no inline asm.
// ---------------------------------------------------------------------------
__global__ __launch_bounds__(512, 1) void lstm_persistent(
    const __bf16* __restrict__ xb,    // (T, B, D) bf16
    const float* __restrict__ W,      // (D, 4H)
    const float* __restrict__ U,      // (H, 4H)
    const float* __restrict__ bias,   // (4H)
    __bf16* __restrict__ hbuf,        // 4 * B * H bf16 (ring)
    float* __restrict__ hlast)        // B * H fp32
{
  const int tid = threadIdx.x;
  const int wg = blockIdx.x;
  const int m_blk = wg & 7;
  const int n_blk = wg >> 3;
  const int wave = tid >> 6;
  const int lane = tid & 63;
  const int q = lane >> 4;     // k-quad
  const int n16 = lane & 15;   // MFMA col within 16-col tile

  __shared__ float Gs[2][8][16][132];  // per-wave gate partials (dbuf)

#define AL(p) __hip_atomic_load(p, __ATOMIC_RELAXED, __HIP_MEMORY_SCOPE_AGENT)
#define AS(p, v) __hip_atomic_store(p, v, __ATOMIC_RELAXED, __HIP_MEMORY_SCOPE_AGENT)
#define MFMA_(a, b, acc) __builtin_amdgcn_mfma_f32_16x16x32_bf16(a, b, acc, 0, 0, 0)

  // ---- Gate-column bases (4 gates x 2 col-halves) ----
  const int nb = n_blk * 32 + n16;
  const int c00 = nb,            c01 = nb + 16;
  const int c10 = NH + nb,       c11 = NH + nb + 16;
  const int c20 = 2 * NH + nb,   c21 = 2 * NH + nb + 16;
  const int c30 = 3 * NH + nb,   c31 = 3 * NH + nb + 16;

  // ---- Persistent B fragments ----
  const float* Wb = W + (wave * 32 + q * 8) * NG;
  bf16x8 BX00 = load_bfrag(Wb + c00), BX01 = load_bfrag(Wb + c01);
  bf16x8 BX10 = load_bfrag(Wb + c10), BX11 = load_bfrag(Wb + c11);
  bf16x8 BX20 = load_bfrag(Wb + c20), BX21 = load_bfrag(Wb + c21);
  bf16x8 BX30 = load_bfrag(Wb + c30), BX31 = load_bfrag(Wb + c31);
  const float* Ub = U + (wave * 128 + q * 8) * NG;
#define DECL_J(J)                                                       \
  bf16x8 BH00##J = load_bfrag(Ub + (J) * 32 * NG + c00);                \
  bf16x8 BH01##J = load_bfrag(Ub + (J) * 32 * NG + c01);                \
  bf16x8 BH10##J = load_bfrag(Ub + (J) * 32 * NG + c10);                \
  bf16x8 BH11##J = load_bfrag(Ub + (J) * 32 * NG + c11);                \
  bf16x8 BH20##J = load_bfrag(Ub + (J) * 32 * NG + c20);                \
  bf16x8 BH21##J = load_bfrag(Ub + (J) * 32 * NG + c21);                \
  bf16x8 BH30##J = load_bfrag(Ub + (J) * 32 * NG + c30);                \
  bf16x8 BH31##J = load_bfrag(Ub + (J) * 32 * NG + c31);
  DECL_J(0) DECL_J(1) DECL_J(2) DECL_J(3)
#undef DECL_J

  // Bias folded into wave 0's accumulator init only (partials are summed)
  const float b00 = (wave == 0) ? bias[c00] : 0.f;
  const float b01 = (wave == 0) ? bias[c01] : 0.f;
  const float b10 = (wave == 0) ? bias[c10] : 0.f;
  const float b11 = (wave == 0) ? bias[c11] : 0.f;
  const float b20 = (wave == 0) ? bias[c20] : 0.f;
  const float b21 = (wave == 0) ? bias[c21] : 0.f;
  const float b30 = (wave == 0) ? bias[c30] : 0.f;
  const float b31 = (wave == 0) ? bias[c31] : 0.f;

  // ---- Elementwise-role constants ----
  const int r_e = tid >> 5;            // 0..15 row
  const int c_e = tid & 31;            // 0..31 h-col
  const int hcol = n_blk * 32 + c_e;
  const int grow = m_blk * 16 + r_e;
  float c_state = 0.0f;

  // Per-lane gather base offset (within a buffer): row m*16+n16, col w*128+q*8
  const int goff = (m_blk * 16 + n16) * NH + (wave << 7) + (q << 3);

  floatx4 AC00, AC01, AC10, AC11, AC20, AC21, AC30, AC31;
#define XPHASE_(XA)                                                     \
  {                                                                     \
    AC00 = (floatx4){b00, b00, b00, b00}; AC01 = (floatx4){b01, b01, b01, b01}; \
    AC10 = (floatx4){b10, b10, b10, b10}; AC11 = (floatx4){b11, b11, b11, b11}; \
    AC20 = (floatx4){b20, b20, b20, b20}; AC21 = (floatx4){b21, b21, b21, b21}; \
    AC30 = (floatx4){b30, b30, b30, b30}; AC31 = (floatx4){b31, b31, b31, b31}; \
    AC00 = MFMA_(XA, BX00, AC00); AC01 = MFMA_(XA, BX01, AC01);         \
    AC10 = MFMA_(XA, BX10, AC10); AC11 = MFMA_(XA, BX11, AC11);         \
    AC20 = MFMA_(XA, BX20, AC20); AC21 = MFMA_(XA, BX21, AC21);         \
    AC30 = MFMA_(XA, BX30, AC30); AC31 = MFMA_(XA, BX31, AC31);         \
  }

  // x A-fragment address for step t (16B contiguous, direct from xb)
#define XFRAG_PTR(T) (const bf16x8*)(xb + ((T) * NB + m_blk * 16 + n16) * ND \
                                     + wave * 32 + q * 8)

  const unsigned long long SGN = 0x8000800080008000ULL;

#define ISSUE_POLL(G)                                                   \
    G##0 = AL(hp); G##1 = AL(hp + 1);                                   \
    G##2 = AL(hp + 8); G##3 = AL(hp + 9);                                \
    G##4 = AL(hp + 16); G##5 = AL(hp + 17);                              \
    G##6 = AL(hp + 24); G##7 = AL(hp + 25);

#define MERGE_POLL(G)                                                   \
    if (m0 & SGN) m0 = G##0; if (m1 & SGN) m1 = G##1;                   \
    if (m2 & SGN) m2 = G##2; if (m3 & SGN) m3 = G##3;                   \
    if (m4 & SGN) m4 = G##4; if (m5 & SGN) m5 = G##5;                   \
    if (m6 & SGN) m6 = G##6; if (m7 & SGN) m7 = G##7;

#define POLL_DONE                                                       \
    __all((((m0 | m1 | m2 | m3 | m4 | m5 | m6 | m7) & SGN) == 0ULL))

  // ---- Prologue: x-phase for t=0; pre-issue gen-A poll on buf0 ----
  const unsigned long long* hp = (const unsigned long long*)(hbuf + goff);
  unsigned long long A0, A1, A2, A3, A4, A5, A6, A7;
  ISSUE_POLL(A)
  {
    bf16x8 x0 = *XFRAG_PTR(0);
    XPHASE_(x0)
  }

  for (int t = 0; t < NT; ++t) {
    // ---- Issue x(t+1) fragment load (consumed at end of this step) ----
    bf16x8 xv;
    if (t < NT - 1) xv = *XFRAG_PTR(t + 1);

    // ---- Pipelined poll+gather of h(t): 2 generations outstanding ----
    unsigned long long m0 = SGN, m1 = SGN, m2 = SGN, m3 = SGN,
                       m4 = SGN, m5 = SGN, m6 = SGN, m7 = SGN;
    MERGE_POLL(A)                      // pre-issued at end of prev step
    if (!POLL_DONE) {
      unsigned long long B0, B1, B2, B3, B4, B5, B6, B7;
      ISSUE_POLL(B)
      while (true) {
        ISSUE_POLL(A)
        MERGE_POLL(B)
        if (POLL_DONE) break;
        ISSUE_POLL(B)
        MERGE_POLL(A)
        if (POLL_DONE) break;
      }
    }
    union { unsigned long long u[2]; bf16x8 v; } u0, u1, u2, u3;
    u0.u[0] = m0; u0.u[1] = m1; u1.u[0] = m2; u1.u[1] = m3;
    u2.u[0] = m4; u2.u[1] = m5; u3.u[0] = m6; u3.u[1] = m7;
    bf16x8 a0 = u0.v, a1 = u1.v, a2 = u2.v, a3 = u3.v;

    // ---- 32 h-MFMAs ----
    AC00 = MFMA_(a0, BH000, AC00); AC01 = MFMA_(a0, BH010, AC01);
    AC10 = MFMA_(a0, BH100, AC10); AC11 = MFMA_(a0, BH110, AC11);
    AC20 = MFMA_(a0, BH200, AC20); AC21 = MFMA_(a0, BH210, AC21);
    AC30 = MFMA_(a0, BH300, AC30); AC31 = MFMA_(a0, BH310, AC31);
    AC00 = MFMA_(a1, BH001, AC00); AC01 = MFMA_(a1, BH011, AC01);
    AC10 = MFMA_(a1, BH101, AC10); AC11 = MFMA_(a1, BH111, AC11);
    AC20 = MFMA_(a1, BH201, AC20); AC21 = MFMA_(a1, BH211, AC21);
    AC30 = MFMA_(a1, BH301, AC30); AC31 = MFMA_(a1, BH311, AC31);
    AC00 = MFMA_(a2, BH002, AC00); AC01 = MFMA_(a2, BH012, AC01);
    AC10 = MFMA_(a2, BH102, AC10); AC11 = MFMA_(a2, BH112, AC11);
    AC20 = MFMA_(a2, BH202, AC20); AC21 = MFMA_(a2, BH212, AC21);
    AC30 = MFMA_(a2, BH302, AC30); AC31 = MFMA_(a2, BH312, AC31);
    AC00 = MFMA_(a3, BH003, AC00); AC01 = MFMA_(a3, BH013, AC01);
    AC10 = MFMA_(a3, BH103, AC10); AC11 = MFMA_(a3, BH113, AC11);
    AC20 = MFMA_(a3, BH203, AC20); AC21 = MFMA_(a3, BH213, AC21);
    AC30 = MFMA_(a3, BH303, AC30); AC31 = MFMA_(a3, BH313, AC31);

    // ---- Reduction: wave partials -> Gs[t&1] ----
    const int gi = t & 1;
#pragma unroll
    for (int rr = 0; rr < 4; ++rr) {
      int row = q * 4 + rr;
      Gs[gi][wave][row][n16]       = AC00[rr];
      Gs[gi][wave][row][16 + n16]  = AC01[rr];
      Gs[gi][wave][row][32 + n16]  = AC10[rr];
      Gs[gi][wave][row][48 + n16]  = AC11[rr];
      Gs[gi][wave][row][64 + n16]  = AC20[rr];
      Gs[gi][wave][row][80 + n16]  = AC21[rr];
      Gs[gi][wave][row][96 + n16]  = AC30[rr];
      Gs[gi][wave][row][112 + n16] = AC31[rr];
    }

    // S2: the only barrier. Its implicit vmcnt drain also makes last step's
    // publish + re-sentinel stores durable before this step's publish.
    __syncthreads();

    // ---- LSTM cell ----
    {
      float xi = 0.f, xf = 0.f, xg = 0.f, xo = 0.f;
#pragma unroll
      for (int w2i = 0; w2i < 8; ++w2i) {
        xi += Gs[gi][w2i][r_e][c_e];
        xf += Gs[gi][w2i][r_e][32 + c_e];
        xg += Gs[gi][w2i][r_e][64 + c_e];
        xo += Gs[gi][w2i][r_e][96 + c_e];
      }
      float iv = fsigmoid_(xi);
      float fv = fsigmoid_(xf);
      float gv = fsoftplus_(xg);
      float ov = fsigmoid_(xo);
      c_state = fv * c_state + iv * gv;
      float hv = ov * fsoftplus_(c_state);   // hv >= 0 always: sign bit 0
      if (t == NT - 1) {
        hlast[grow * NH + hcol] = hv;
      } else {
        // 8B packed publish into buf (t+1)&3: 2x shfl_xor, lanes c_e%4==0
        float hn1 = __shfl_xor(hv, 1);
        __hip_bfloat162 pk;
        pk.x = (__hip_bfloat16)hv; pk.y = (__hip_bfloat16)hn1;
        unsigned int pw = *(unsigned int*)&pk;
        unsigned int po = (unsigned int)__shfl_xor((int)pw, 2);
        if ((c_e & 3) == 0) {
          unsigned long long vv = ((unsigned long long)po << 32) | pw;
          AS((unsigned long long*)(hbuf + ((t + 1) & 3) * (NB * NH)
                                   + grow * NH + hcol), vv);
          // Re-sentinel my patch of buf (t+3)&3 (held h(t-1), now dead).
          AS((unsigned long long*)(hbuf + ((t + 3) & 3) * (NB * NH)
                                   + grow * NH + hcol),
             0xFFFFFFFFFFFFFFFFULL);
        }
      }
    }

    if (t < NT - 1) {
      // ---- Pre-issue gen-A poll for step t+1 (flies during XPHASE) ----
      hp = (const unsigned long long*)(hbuf + ((t + 1) & 3) * (NB * NH) + goff);
      ISSUE_POLL(A)
      // ---- Hidden work while publish + first sample round-trip ----
      XPHASE_(xv)
    }
  }
#undef POLL_DONE
#undef MERGE_POLL
#undef ISSUE_POLL
#undef XFRAG_PTR
#undef XPHASE_
#undef AS
#undef AL
#undef MFMA_
}

// ---------------------------------------------------------------------------
// Kernel 3: projection head. 32 blocks x 128 thr; 4 batch rows per block.
// ---------------------------------------------------------------------------
__global__ __launch_bounds__(128) void proj_kernel(
    const float* __restrict__ hlast,
    const float* __restrict__ Wm, const float* __restrict__ bm,
    const float* __restrict__ Wv, const float* __restrict__ bv,
    const float* __restrict__ eps, float* __restrict__ out) {
  __shared__ float hs[4][NH];
  const int bb = blockIdx.x * 4;
  for (int idx = threadIdx.x; idx < 4 * NH; idx += 128)
    hs[idx >> 10][idx & (NH - 1)] = hlast[(bb + (idx >> 10)) * NH + (idx & (NH - 1))];
  __syncthreads();
  const int z = threadIdx.x;
  float am[4] = {0.f, 0.f, 0.f, 0.f};
  float av[4] = {0.f, 0.f, 0.f, 0.f};
#pragma unroll 8
  for (int k = 0; k < NH; ++k) {
    float wm = Wm[k * NZ + z];
    float wv = Wv[k * NZ + z];
#pragma unroll
    for (int r = 0; r < 4; ++r) {
      am[r] += hs[r][k] * wm;
      av[r] += hs[r][k] * wv;
    }
  }
#pragma unroll
  for (int r = 0; r < 4; ++r) {
    int b = bb + r;
    float mu = am[r] + bm[z];
    float lv = av[r] + bv[z];
    float zz = mu + eps[b * NZ + z] * expf(0.5f * lv);
    out[b * NZ + z] = mu;
    out[NB * NZ + b * NZ + z] = lv;
    out[2 * NB * NZ + b * NZ + z] = zz;
  }
}

// ---------------------------------------------------------------------------
extern "C" void kernel_launch(void* const* d_in, const int* in_sizes, int n_in,
                              void* d_out, int out_size, void* d_ws, size_t ws_size,
                              hipStream_t stream) {
  const float* x   = (const float*)d_in[0];
  const float* W   = (const float*)d_in[1];
  const float* U   = (const float*)d_in[2];
  const float* b   = (const float*)d_in[3];
  const float* Wm  = (const float*)d_in[4];
  const float* bm  = (const float*)d_in[5];
  const float* Wv  = (const float*)d_in[6];
  const float* bv  = (const float*)d_in[7];
  const float* eps = (const float*)d_in[8];

  // Workspace layout:
  //   [0,       1048576)   hbuf: 4-deep ring of B x H bf16 (256KB each)
  //   [1048576, +33.5MB)   xb: T x B x D bf16
  //   hlast (B x H fp32, 512KB) ALIASES xb's t<8 region: x(t<8) is dead
  //   after step 7; hlast is written only at step NT-1.
  char* ws = (char*)d_ws;
  __bf16* hbuf = (__bf16*)ws;
  __bf16* xb   = (__bf16*)(ws + 1048576);
  float* hlast = (float*)(ws + 1048576);

  // buf0 = h(0) = 0 (sign-clear = "present"); bufs 1..3 = 0xFFFF sentinel.
  hipMemsetAsync(hbuf, 0, NB * NH * sizeof(__bf16), stream);
  hipMemsetAsync(hbuf + NB * NH, 0xFF, 3 * NB * NH * sizeof(__bf16), stream);

  convert_x_kernel<<<dim3((NB * NT * ND) / 4 / 256), dim3(256), 0, stream>>>(
      (const float4*)x, xb);

  void* args[] = {(void*)&xb, (void*)&W, (void*)&U, (void*)&b,
                  (void*)&hbuf, (void*)&hlast};
  hipLaunchCooperativeKernel(reinterpret_cast<void*>(lstm_persistent),
                             dim3(256), dim3(512), args, 0, stream);

  proj_kernel<<<dim3(32), dim3(128), 0, stream>>>(hlast, Wm, bm, Wv, bv, eps,
                                                  (float*)d_out);
}

// Round 8
// 2973.996 us; speedup vs baseline: 2.4407x; 1.1245x over previous
//
#include <hip/hip_runtime.h>
#include <hip/hip_bf16.h>
#include <stdint.h>

// Problem constants
#define NB 128    // batch
#define NT 512    // time steps
#define ND 256    // input dim
#define NH 1024   // hidden dim
#define NZ 128    // latent dim
#define NG 4096   // 4*NH gate width

typedef __attribute__((ext_vector_type(8))) __bf16 bf16x8;
typedef __attribute__((ext_vector_type(4))) __bf16 bf16x4;
typedef __attribute__((ext_vector_type(4))) float floatx4;

// Fast native transcendentals (v_exp_f32 / v_log_f32 / v_rcp_f32).
__device__ __forceinline__ float fsigmoid_(float x) {
  return __fdividef(1.0f, 1.0f + __expf(-x));
}
__device__ __forceinline__ float fsoftplus_(float x) {
  return fmaxf(x, 0.0f) + __logf(1.0f + __expf(-fabsf(x)));
}

// B-fragment loader: 8 fp32 rows (stride NG) -> bf16x8
__device__ __forceinline__ bf16x8 load_bfrag(const float* s) {
  bf16x8 v;
#pragma unroll
  for (int jj = 0; jj < 8; ++jj) v[jj] = (__bf16)s[jj * NG];
  return v;
}

// ---------------------------------------------------------------------------
// Kernel 1: convert x (B,T,D) fp32 -> xb (T,B,D) bf16
// ---------------------------------------------------------------------------
__global__ __launch_bounds__(256) void convert_x_kernel(
    const float4* __restrict__ x, __bf16* __restrict__ xb) {
  int i = blockIdx.x * 256 + threadIdx.x;
  int d4 = i & 63;
  int bt = i >> 6;
  int b = bt >> 9;
  int t = bt & 511;
  float4 v = x[i];
  bf16x4 o;
  o[0] = (__bf16)v.x; o[1] = (__bf16)v.y; o[2] = (__bf16)v.z; o[3] = (__bf16)v.w;
  *(bf16x4*)(xb + ((t * NB + b) * ND + d4 * 4)) = o;
}

// ---------------------------------------------------------------------------
// Kernel 2: persistent LSTM — R17: sentinel sync + lazy poll (R14 traffic
// discipline) + (a) ONE pre-issued poll generation + (b) eager per-slice
// MFMA inside the poll loop.
//
// Grid 256 WGs x 512 thr (1 WG/CU, m_blk = wg&7, n_blk = wg>>3). Clique for
// batch-group m = the 32 WGs {wg : wg&7==m}; each WG publishes a 16x32 h
// patch and gathers the full 16x1024 h row-block each step. Wave w's lanes
// read cols [w*128,+128) = patches of producers n' in {4w..4w+3}: each
// k-slice j (words 2j,2j+1 per lane) comes from exactly ONE producer WG.
//
// KEY INVARIANT: h = sigmoid(o)*softplus(c) >= 0, so every published bf16
// has SIGN BIT 0. hbuf is a 4-deep ring; unwritten/retired buffers hold
// 0xFFFF (sign set). Consumers poll THE GATHER WORDS THEMSELVES:
// (w & 0x8000'8000'8000'8000) == 0 <=> that 8B word is fresh h. Each 8B
// word is single-writer-atomic and single-assignment per ring slot per
// step, so ANY sign-clear sample is the final value.
//
// R17 poll discipline (traffic == R14 + 1 sample/step):
//  (a) PRE-ISSUE: the 8 gather loads for step t+1 are issued once at the
//      END of step t (after publish, before XPHASE) — first sample flies
//      during XPHASE. Safety: pre-issue happens after this WG detected
//      full h(t); every peer's re-arm of buf (t+1)&3 (done at its step
//      t-2, drained by its t-1 barrier) reached the LLC before its h(t)
//      publish, so the pre-issued read can only see sentinel or h(t+1).
//      (Protocol identical to R16, which passed correctness.)
//  (b) EAGER SLICES: inside the lazy loop, each k-slice is checked
//      independently (wave-uniform __all) and its 8 MFMAs run as soon as
//      that slice is fresh — early producers' matmuls overlap waiting for
//      stragglers. Lazy reload (only still-sentinel words) + s_sleep(1)
//      retained verbatim from R14 (R16 proved hot polling congests LLC).
//
// Re-arm protocol unchanged: at step t, after detecting full h(t),
// re-sentinel own patch of buf (t+3)&3 (held h(t-1), dead). __syncthreads'
// implicit vmcnt drain orders re-arm/publish stores across steps.
// Loop: [merge pre-issued gen / eager-slice lazy poll h(t), MFMAs inside]
// -> reduce Gs[t&1] -> __syncthreads (ONLY barrier) -> cell -> publish
// h(t+1) -> re-sentinel -> pre-issue for t+1 -> XPHASE(t+1).
// All comms = agent-scope relaxed atomics; no inline asm.
// ---------------------------------------------------------------------------
__global__ __launch_bounds__(512, 1) void lstm_persistent(
    const __bf16* __restrict__ xb,    // (T, B, D) bf16
    const float* __restrict__ W,      // (D, 4H)
    const float* __restrict__ U,      // (H, 4H)
    const float* __restrict__ bias,   // (4H)
    __bf16* __restrict__ hbuf,        // 4 * B * H bf16 (ring)
    float* __restrict__ hlast)        // B * H fp32
{
  const int tid = threadIdx.x;
  const int wg = blockIdx.x;
  const int m_blk = wg & 7;
  const int n_blk = wg >> 3;
  const int wave = tid >> 6;
  const int lane = tid & 63;
  const int q = lane >> 4;     // k-quad
  const int n16 = lane & 15;   // MFMA col within 16-col tile

  __shared__ float Gs[2][8][16][132];  // per-wave gate partials (dbuf)

#define AL(p) __hip_atomic_load(p, __ATOMIC_RELAXED, __HIP_MEMORY_SCOPE_AGENT)
#define AS(p, v) __hip_atomic_store(p, v, __ATOMIC_RELAXED, __HIP_MEMORY_SCOPE_AGENT)
#define MFMA_(a, b, acc) __builtin_amdgcn_mfma_f32_16x16x32_bf16(a, b, acc, 0, 0, 0)

  // ---- Gate-column bases (4 gates x 2 col-halves) ----
  const int nb = n_blk * 32 + n16;
  const int c00 = nb,            c01 = nb + 16;
  const int c10 = NH + nb,       c11 = NH + nb + 16;
  const int c20 = 2 * NH + nb,   c21 = 2 * NH + nb + 16;
  const int c30 = 3 * NH + nb,   c31 = 3 * NH + nb + 16;

  // ---- Persistent B fragments ----
  const float* Wb = W + (wave * 32 + q * 8) * NG;
  bf16x8 BX00 = load_bfrag(Wb + c00), BX01 = load_bfrag(Wb + c01);
  bf16x8 BX10 = load_bfrag(Wb + c10), BX11 = load_bfrag(Wb + c11);
  bf16x8 BX20 = load_bfrag(Wb + c20), BX21 = load_bfrag(Wb + c21);
  bf16x8 BX30 = load_bfrag(Wb + c30), BX31 = load_bfrag(Wb + c31);
  const float* Ub = U + (wave * 128 + q * 8) * NG;
#define DECL_J(J)                                                       \
  bf16x8 BH00##J = load_bfrag(Ub + (J) * 32 * NG + c00);                \
  bf16x8 BH01##J = load_bfrag(Ub + (J) * 32 * NG + c01);                \
  bf16x8 BH10##J = load_bfrag(Ub + (J) * 32 * NG + c10);                \
  bf16x8 BH11##J = load_bfrag(Ub + (J) * 32 * NG + c11);                \
  bf16x8 BH20##J = load_bfrag(Ub + (J) * 32 * NG + c20);                \
  bf16x8 BH21##J = load_bfrag(Ub + (J) * 32 * NG + c21);                \
  bf16x8 BH30##J = load_bfrag(Ub + (J) * 32 * NG + c30);                \
  bf16x8 BH31##J = load_bfrag(Ub + (J) * 32 * NG + c31);
  DECL_J(0) DECL_J(1) DECL_J(2) DECL_J(3)
#undef DECL_J

  // Bias folded into wave 0's accumulator init only (partials are summed)
  const float b00 = (wave == 0) ? bias[c00] : 0.f;
  const float b01 = (wave == 0) ? bias[c01] : 0.f;
  const float b10 = (wave == 0) ? bias[c10] : 0.f;
  const float b11 = (wave == 0) ? bias[c11] : 0.f;
  const float b20 = (wave == 0) ? bias[c20] : 0.f;
  const float b21 = (wave == 0) ? bias[c21] : 0.f;
  const float b30 = (wave == 0) ? bias[c30] : 0.f;
  const float b31 = (wave == 0) ? bias[c31] : 0.f;

  // ---- Elementwise-role constants ----
  const int r_e = tid >> 5;            // 0..15 row
  const int c_e = tid & 31;            // 0..31 h-col
  const int hcol = n_blk * 32 + c_e;
  const int grow = m_blk * 16 + r_e;
  float c_state = 0.0f;

  // Per-lane gather base offset (within a buffer): row m*16+n16, col w*128+q*8
  const int goff = (m_blk * 16 + n16) * NH + (wave << 7) + (q << 3);

  floatx4 AC00, AC01, AC10, AC11, AC20, AC21, AC30, AC31;
#define XPHASE_(XA)                                                     \
  {                                                                     \
    AC00 = (floatx4){b00, b00, b00, b00}; AC01 = (floatx4){b01, b01, b01, b01}; \
    AC10 = (floatx4){b10, b10, b10, b10}; AC11 = (floatx4){b11, b11, b11, b11}; \
    AC20 = (floatx4){b20, b20, b20, b20}; AC21 = (floatx4){b21, b21, b21, b21}; \
    AC30 = (floatx4){b30, b30, b30, b30}; AC31 = (floatx4){b31, b31, b31, b31}; \
    AC00 = MFMA_(XA, BX00, AC00); AC01 = MFMA_(XA, BX01, AC01);         \
    AC10 = MFMA_(XA, BX10, AC10); AC11 = MFMA_(XA, BX11, AC11);         \
    AC20 = MFMA_(XA, BX20, AC20); AC21 = MFMA_(XA, BX21, AC21);         \
    AC30 = MFMA_(XA, BX30, AC30); AC31 = MFMA_(XA, BX31, AC31);         \
  }

  // 8 h-MFMAs for k-slice J (one producer WG's patch), from merge words
#define HSLICE(J, WA, WB)                                               \
  {                                                                     \
    union { unsigned long long u[2]; bf16x8 v; } uu;                    \
    uu.u[0] = (WA); uu.u[1] = (WB);                                     \
    bf16x8 aa = uu.v;                                                   \
    AC00 = MFMA_(aa, BH00##J, AC00); AC01 = MFMA_(aa, BH01##J, AC01);   \
    AC10 = MFMA_(aa, BH10##J, AC10); AC11 = MFMA_(aa, BH11##J, AC11);   \
    AC20 = MFMA_(aa, BH20##J, AC20); AC21 = MFMA_(aa, BH21##J, AC21);   \
    AC30 = MFMA_(aa, BH30##J, AC30); AC31 = MFMA_(aa, BH31##J, AC31);   \
  }

  // x A-fragment address for step t (16B contiguous, direct from xb)
#define XFRAG_PTR(T) (const bf16x8*)(xb + ((T) * NB + m_blk * 16 + n16) * ND \
                                     + wave * 32 + q * 8)

#define PRE_ISSUE()                                                     \
    A0 = AL(hp); A1 = AL(hp + 1);                                       \
    A2 = AL(hp + 8); A3 = AL(hp + 9);                                   \
    A4 = AL(hp + 16); A5 = AL(hp + 17);                                 \
    A6 = AL(hp + 24); A7 = AL(hp + 25);

  const unsigned long long SGN = 0x8000800080008000ULL;

  // ---- Prologue: pre-issue poll on buf0 (h(0)=0, fresh); x-phase t=0 ----
  const unsigned long long* hp = (const unsigned long long*)(hbuf + goff);
  unsigned long long A0, A1, A2, A3, A4, A5, A6, A7;
  PRE_ISSUE()
  {
    bf16x8 x0 = *XFRAG_PTR(0);
    XPHASE_(x0)
  }

  for (int t = 0; t < NT; ++t) {
    // ---- Issue x(t+1) fragment load (consumed at end of this step) ----
    bf16x8 xv;
    if (t < NT - 1) xv = *XFRAG_PTR(t + 1);

    // ---- Eager-slice lazy poll+gather of h(t) ----
    // Initial samples = the pre-issued generation (in flight since the end
    // of the previous step). Then R14's lazy reload + sleep discipline.
    {
      unsigned long long m0 = A0, m1 = A1, m2 = A2, m3 = A3,
                         m4 = A4, m5 = A5, m6 = A6, m7 = A7;
      bool d0 = false, d1 = false, d2 = false, d3 = false;
      while (true) {
        if (!d0 && __all((int)(((m0 | m1) & SGN) == 0ULL))) {
          d0 = true; HSLICE(0, m0, m1)
        }
        if (!d1 && __all((int)(((m2 | m3) & SGN) == 0ULL))) {
          d1 = true; HSLICE(1, m2, m3)
        }
        if (!d2 && __all((int)(((m4 | m5) & SGN) == 0ULL))) {
          d2 = true; HSLICE(2, m4, m5)
        }
        if (!d3 && __all((int)(((m6 | m7) & SGN) == 0ULL))) {
          d3 = true; HSLICE(3, m6, m7)
        }
        if (d0 && d1 && d2 && d3) break;
        __builtin_amdgcn_s_sleep(1);
        if (m0 & SGN) m0 = AL(hp);
        if (m1 & SGN) m1 = AL(hp + 1);
        if (m2 & SGN) m2 = AL(hp + 8);
        if (m3 & SGN) m3 = AL(hp + 9);
        if (m4 & SGN) m4 = AL(hp + 16);
        if (m5 & SGN) m5 = AL(hp + 17);
        if (m6 & SGN) m6 = AL(hp + 24);
        if (m7 & SGN) m7 = AL(hp + 25);
      }
    }

    // ---- Reduction: wave partials -> Gs[t&1] ----
    const int gi = t & 1;
#pragma unroll
    for (int rr = 0; rr < 4; ++rr) {
      int row = q * 4 + rr;
      Gs[gi][wave][row][n16]       = AC00[rr];
      Gs[gi][wave][row][16 + n16]  = AC01[rr];
      Gs[gi][wave][row][32 + n16]  = AC10[rr];
      Gs[gi][wave][row][48 + n16]  = AC11[rr];
      Gs[gi][wave][row][64 + n16]  = AC20[rr];
      Gs[gi][wave][row][80 + n16]  = AC21[rr];
      Gs[gi][wave][row][96 + n16]  = AC30[rr];
      Gs[gi][wave][row][112 + n16] = AC31[rr];
    }

    // S2: the only barrier. Its implicit vmcnt drain also makes last step's
    // publish + re-sentinel stores durable before this step's publish.
    __syncthreads();

    // ---- LSTM cell ----
    {
      float xi = 0.f, xf = 0.f, xg = 0.f, xo = 0.f;
#pragma unroll
      for (int w2i = 0; w2i < 8; ++w2i) {
        xi += Gs[gi][w2i][r_e][c_e];
        xf += Gs[gi][w2i][r_e][32 + c_e];
        xg += Gs[gi][w2i][r_e][64 + c_e];
        xo += Gs[gi][w2i][r_e][96 + c_e];
      }
      float iv = fsigmoid_(xi);
      float fv = fsigmoid_(xf);
      float gv = fsoftplus_(xg);
      float ov = fsigmoid_(xo);
      c_state = fv * c_state + iv * gv;
      float hv = ov * fsoftplus_(c_state);   // hv >= 0 always: sign bit 0
      if (t == NT - 1) {
        hlast[grow * NH + hcol] = hv;
      } else {
        // 8B packed publish into buf (t+1)&3: 2x shfl_xor, lanes c_e%4==0
        float hn1 = __shfl_xor(hv, 1);
        __hip_bfloat162 pk;
        pk.x = (__hip_bfloat16)hv; pk.y = (__hip_bfloat16)hn1;
        unsigned int pw = *(unsigned int*)&pk;
        unsigned int po = (unsigned int)__shfl_xor((int)pw, 2);
        if ((c_e & 3) == 0) {
          unsigned long long vv = ((unsigned long long)po << 32) | pw;
          AS((unsigned long long*)(hbuf + ((t + 1) & 3) * (NB * NH)
                                   + grow * NH + hcol), vv);
          // Re-sentinel my patch of buf (t+3)&3 (held h(t-1), now dead).
          AS((unsigned long long*)(hbuf + ((t + 3) & 3) * (NB * NH)
                                   + grow * NH + hcol),
             0xFFFFFFFFFFFFFFFFULL);
        }
      }
    }

    if (t < NT - 1) {
      // ---- Pre-issue the single poll generation for t+1 (flies during
      //      XPHASE; safety per header comment) ----
      hp = (const unsigned long long*)(hbuf + ((t + 1) & 3) * (NB * NH) + goff);
      PRE_ISSUE()
      // ---- Hidden work while publish + first sample round-trip ----
      XPHASE_(xv)
    }
  }
#undef PRE_ISSUE
#undef XFRAG_PTR
#undef HSLICE
#undef XPHASE_
#undef AS
#undef AL
#undef MFMA_
}

// ---------------------------------------------------------------------------
// Kernel 3: projection head. 32 blocks x 128 thr; 4 batch rows per block.
// ---------------------------------------------------------------------------
__global__ __launch_bounds__(128) void proj_kernel(
    const float* __restrict__ hlast,
    const float* __restrict__ Wm, const float* __restrict__ bm,
    const float* __restrict__ Wv, const float* __restrict__ bv,
    const float* __restrict__ eps, float* __restrict__ out) {
  __shared__ float hs[4][NH];
  const int bb = blockIdx.x * 4;
  for (int idx = threadIdx.x; idx < 4 * NH; idx += 128)
    hs[idx >> 10][idx & (NH - 1)] = hlast[(bb + (idx >> 10)) * NH + (idx & (NH - 1))];
  __syncthreads();
  const int z = threadIdx.x;
  float am[4] = {0.f, 0.f, 0.f, 0.f};
  float av[4] = {0.f, 0.f, 0.f, 0.f};
#pragma unroll 8
  for (int k = 0; k < NH; ++k) {
    float wm = Wm[k * NZ + z];
    float wv = Wv[k * NZ + z];
#pragma unroll
    for (int r = 0; r < 4; ++r) {
      am[r] += hs[r][k] * wm;
      av[r] += hs[r][k] * wv;
    }
  }
#pragma unroll
  for (int r = 0; r < 4; ++r) {
    int b = bb + r;
    float mu = am[r] + bm[z];
    float lv = av[r] + bv[z];
    float zz = mu + eps[b * NZ + z] * expf(0.5f * lv);
    out[b * NZ + z] = mu;
    out[NB * NZ + b * NZ + z] = lv;
    out[2 * NB * NZ + b * NZ + z] = zz;
  }
}

// ---------------------------------------------------------------------------
extern "C" void kernel_launch(void* const* d_in, const int* in_sizes, int n_in,
                              void* d_out, int out_size, void* d_ws, size_t ws_size,
                              hipStream_t stream) {
  const float* x   = (const float*)d_in[0];
  const float* W   = (const float*)d_in[1];
  const float* U   = (const float*)d_in[2];
  const float* b   = (const float*)d_in[3];
  const float* Wm  = (const float*)d_in[4];
  const float* bm  = (const float*)d_in[5];
  const float* Wv  = (const float*)d_in[6];
  const float* bv  = (const float*)d_in[7];
  const float* eps = (const float*)d_in[8];

  // Workspace layout:
  //   [0,       1048576)   hbuf: 4-deep ring of B x H bf16 (256KB each)
  //   [1048576, +33.5MB)   xb: T x B x D bf16
  //   hlast (B x H fp32, 512KB) ALIASES xb's t<8 region: x(t<8) is dead
  //   after step 7; hlast is written only at step NT-1.
  char* ws = (char*)d_ws;
  __bf16* hbuf = (__bf16*)ws;
  __bf16* xb   = (__bf16*)(ws + 1048576);
  float* hlast = (float*)(ws + 1048576);

  // buf0 = h(0) = 0 (sign-clear = "present"); bufs 1..3 = 0xFFFF sentinel.
  hipMemsetAsync(hbuf, 0, NB * NH * sizeof(__bf16), stream);
  hipMemsetAsync(hbuf + NB * NH, 0xFF, 3 * NB * NH * sizeof(__bf16), stream);

  convert_x_kernel<<<dim3((NB * NT * ND) / 4 / 256), dim3(256), 0, stream>>>(
      (const float4*)x, xb);

  void* args[] = {(void*)&xb, (void*)&W, (void*)&U, (void*)&b,
                  (void*)&hbuf, (void*)&hlast};
  hipLaunchCooperativeKernel(reinterpret_cast<void*>(lstm_persistent),
                             dim3(256), dim3(512), args, 0, stream);

  proj_kernel<<<dim3(32), dim3(128), 0, stream>>>(hlast, Wm, bm, Wv, bv, eps,
                                                  (float*)d_out);
}

// Round 9
// 2351.262 us; speedup vs baseline: 3.0871x; 1.2649x over previous
//
#include <hip/hip_runtime.h>
#include <hip/hip_bf16.h>
#include <stdint.h>

// Problem constants
#define NB 128    // batch
#define NT 512    // time steps
#define ND 256    // input dim
#define NH 1024   // hidden dim
#define NZ 128    // latent dim
#define NG 4096   // 4*NH gate width

typedef __attribute__((ext_vector_type(8))) __bf16 bf16x8;
typedef __attribute__((ext_vector_type(4))) __bf16 bf16x4;
typedef __attribute__((ext_vector_type(4))) float floatx4;

// Fast native transcendentals (v_exp_f32 / v_log_f32 / v_rcp_f32).
__device__ __forceinline__ float fsigmoid_(float x) {
  return __fdividef(1.0f, 1.0f + __expf(-x));
}
__device__ __forceinline__ float fsoftplus_(float x) {
  return fmaxf(x, 0.0f) + __logf(1.0f + __expf(-fabsf(x)));
}

// B-fragment loader: 8 fp32 rows (stride NG) -> bf16x8
__device__ __forceinline__ bf16x8 load_bfrag(const float* s) {
  bf16x8 v;
#pragma unroll
  for (int jj = 0; jj < 8; ++jj) v[jj] = (__bf16)s[jj * NG];
  return v;
}

// ---------------------------------------------------------------------------
// Kernel 1: convert x (B,T,D) fp32 -> xb (T,B,D) bf16
// ---------------------------------------------------------------------------
__global__ __launch_bounds__(256) void convert_x_kernel(
    const float4* __restrict__ x, __bf16* __restrict__ xb) {
  int i = blockIdx.x * 256 + threadIdx.x;
  int d4 = i & 63;
  int bt = i >> 6;
  int b = bt >> 9;
  int t = bt & 511;
  float4 v = x[i];
  bf16x4 o;
  o[0] = (__bf16)v.x; o[1] = (__bf16)v.y; o[2] = (__bf16)v.z; o[3] = (__bf16)v.w;
  *(bf16x4*)(xb + ((t * NB + b) * ND + d4 * 4)) = o;
}

// ---------------------------------------------------------------------------
// Kernel 2: persistent LSTM — R19: R14 verbatim + geometric poll BACKOFF.
// (R17's pre-issue/eager-slice reverted — it lengthened the detect path.)
//
// Grid 256 WGs x 512 thr (1 WG/CU, m_blk = wg&7, n_blk = wg>>3). Clique for
// batch-group m = the 32 WGs {wg : wg&7==m}; each WG publishes a 16x32 h
// patch and gathers the full 16x1024 h row-block each step.
//
// KEY INVARIANT: h = sigmoid(o)*softplus(c) >= 0, so every published bf16
// has SIGN BIT 0. hbuf is a 4-deep ring; unwritten/retired buffers hold
// 0xFFFF (sign set). Consumers poll THE GATHER WORDS THEMSELVES:
// (w & 0x8000'8000'8000'8000) == 0 <=> that 8B word is fresh h. Each 8B
// word is single-writer-atomic and single-assignment per ring slot per
// step, so once a word reads fresh its value is FINAL — lanes reload only
// words still showing sentinel (lazy re-poll, R14).
//
// R19 change: the inter-generation s_sleep backs off geometrically
// (1,2,4 then cap 8 x64cy). Rationale: the step period is dominated by
// publish-store VISIBILITY, and the leading mechanism is hot-line write
// starvation at the LLC — consumers re-read the producer's lines every
// ~0.3us (sleep(1) is nearly hot), and the publish store must win
// arbitration against that read stream. Backoff decongests the hot lines;
// worst-case cost if the theory is wrong is ~cap/2 = 0.1us/step of detect
// quantization. (s_sleep needs an immediate -> unrolled uniform branch.)
//
// Re-arm protocol (single-writer per word; WG (m,n) owns its patch in every
// buffer): at step t, after detecting full h(t), re-sentinel own patch of
// buf (t+3)&3 (which held h(t-1)). Safety: full h(t) present => every
// clique WG published h(t) => each completed gather(t-1), so h(t-1) is
// dead. Durability: __syncthreads drains vmcnt, so the step-t re-sentinel
// is durable before h(t+2) (issued after S2(t+1)) exists. Buf ring: h(t)
// lives in buf t&3; buf0 = h(0) = zeros, bufs 1..3 memset 0xFF.
//
// Loop: [issue x(t+1) frag load] -> lazy poll/gather h(t) w/ backoff ->
// 32 h-MFMAs -> reduce Gs[t&1] -> __syncthreads (ONLY barrier) -> cell ->
// publish h(t+1) -> re-sentinel buf (t+3)&3 -> XPHASE(t+1).
// All comms = agent-scope relaxed atomics; no inline asm.
// ---------------------------------------------------------------------------
__global__ __launch_bounds__(512, 1) void lstm_persistent(
    const __bf16* __restrict__ xb,    // (T, B, D) bf16
    const float* __restrict__ W,      // (D, 4H)
    const float* __restrict__ U,      // (H, 4H)
    const float* __restrict__ bias,   // (4H)
    __bf16* __restrict__ hbuf,        // 4 * B * H bf16 (ring)
    float* __restrict__ hlast)        // B * H fp32
{
  const int tid = threadIdx.x;
  const int wg = blockIdx.x;
  const int m_blk = wg & 7;
  const int n_blk = wg >> 3;
  const int wave = tid >> 6;
  const int lane = tid & 63;
  const int q = lane >> 4;     // k-quad
  const int n16 = lane & 15;   // MFMA col within 16-col tile

  __shared__ float Gs[2][8][16][132];  // per-wave gate partials (dbuf)

#define AL(p) __hip_atomic_load(p, __ATOMIC_RELAXED, __HIP_MEMORY_SCOPE_AGENT)
#define AS(p, v) __hip_atomic_store(p, v, __ATOMIC_RELAXED, __HIP_MEMORY_SCOPE_AGENT)
#define MFMA_(a, b, acc) __builtin_amdgcn_mfma_f32_16x16x32_bf16(a, b, acc, 0, 0, 0)

  // ---- Gate-column bases (4 gates x 2 col-halves) ----
  const int nb = n_blk * 32 + n16;
  const int c00 = nb,            c01 = nb + 16;
  const int c10 = NH + nb,       c11 = NH + nb + 16;
  const int c20 = 2 * NH + nb,   c21 = 2 * NH + nb + 16;
  const int c30 = 3 * NH + nb,   c31 = 3 * NH + nb + 16;

  // ---- Persistent B fragments ----
  const float* Wb = W + (wave * 32 + q * 8) * NG;
  bf16x8 BX00 = load_bfrag(Wb + c00), BX01 = load_bfrag(Wb + c01);
  bf16x8 BX10 = load_bfrag(Wb + c10), BX11 = load_bfrag(Wb + c11);
  bf16x8 BX20 = load_bfrag(Wb + c20), BX21 = load_bfrag(Wb + c21);
  bf16x8 BX30 = load_bfrag(Wb + c30), BX31 = load_bfrag(Wb + c31);
  const float* Ub = U + (wave * 128 + q * 8) * NG;
#define DECL_J(J)                                                       \
  bf16x8 BH00##J = load_bfrag(Ub + (J) * 32 * NG + c00);                \
  bf16x8 BH01##J = load_bfrag(Ub + (J) * 32 * NG + c01);                \
  bf16x8 BH10##J = load_bfrag(Ub + (J) * 32 * NG + c10);                \
  bf16x8 BH11##J = load_bfrag(Ub + (J) * 32 * NG + c11);                \
  bf16x8 BH20##J = load_bfrag(Ub + (J) * 32 * NG + c20);                \
  bf16x8 BH21##J = load_bfrag(Ub + (J) * 32 * NG + c21);                \
  bf16x8 BH30##J = load_bfrag(Ub + (J) * 32 * NG + c30);                \
  bf16x8 BH31##J = load_bfrag(Ub + (J) * 32 * NG + c31);
  DECL_J(0) DECL_J(1) DECL_J(2) DECL_J(3)
#undef DECL_J

  // Bias folded into wave 0's accumulator init only (partials are summed)
  const float b00 = (wave == 0) ? bias[c00] : 0.f;
  const float b01 = (wave == 0) ? bias[c01] : 0.f;
  const float b10 = (wave == 0) ? bias[c10] : 0.f;
  const float b11 = (wave == 0) ? bias[c11] : 0.f;
  const float b20 = (wave == 0) ? bias[c20] : 0.f;
  const float b21 = (wave == 0) ? bias[c21] : 0.f;
  const float b30 = (wave == 0) ? bias[c30] : 0.f;
  const float b31 = (wave == 0) ? bias[c31] : 0.f;

  // ---- Elementwise-role constants ----
  const int r_e = tid >> 5;            // 0..15 row
  const int c_e = tid & 31;            // 0..31 h-col
  const int hcol = n_blk * 32 + c_e;
  const int grow = m_blk * 16 + r_e;
  float c_state = 0.0f;

  // Per-lane gather base offset (within a buffer): row m*16+n16, col w*128+q*8
  const int goff = (m_blk * 16 + n16) * NH + (wave << 7) + (q << 3);

  floatx4 AC00, AC01, AC10, AC11, AC20, AC21, AC30, AC31;
#define XPHASE_(XA)                                                     \
  {                                                                     \
    AC00 = (floatx4){b00, b00, b00, b00}; AC01 = (floatx4){b01, b01, b01, b01}; \
    AC10 = (floatx4){b10, b10, b10, b10}; AC11 = (floatx4){b11, b11, b11, b11}; \
    AC20 = (floatx4){b20, b20, b20, b20}; AC21 = (floatx4){b21, b21, b21, b21}; \
    AC30 = (floatx4){b30, b30, b30, b30}; AC31 = (floatx4){b31, b31, b31, b31}; \
    AC00 = MFMA_(XA, BX00, AC00); AC01 = MFMA_(XA, BX01, AC01);         \
    AC10 = MFMA_(XA, BX10, AC10); AC11 = MFMA_(XA, BX11, AC11);         \
    AC20 = MFMA_(XA, BX20, AC20); AC21 = MFMA_(XA, BX21, AC21);         \
    AC30 = MFMA_(XA, BX30, AC30); AC31 = MFMA_(XA, BX31, AC31);         \
  }

  // x A-fragment address for step t (16B contiguous, direct from xb)
#define XFRAG_PTR(T) (const bf16x8*)(xb + ((T) * NB + m_blk * 16 + n16) * ND \
                                     + wave * 32 + q * 8)

  // ---- Prologue: x-phase for t=0 (no LDS, no barrier needed) ----
  {
    bf16x8 x0 = *XFRAG_PTR(0);
    XPHASE_(x0)
  }

  const unsigned long long SGN = 0x8000800080008000ULL;

  for (int t = 0; t < NT; ++t) {
    // ---- Issue x(t+1) fragment load (consumed at end of this step) ----
    bf16x8 xv;
    if (t < NT - 1) xv = *XFRAG_PTR(t + 1);

    // ---- Lazy poll+gather of h(t) with geometric backoff ----
    unsigned long long w0 = SGN, w1 = SGN, w2 = SGN, w3 = SGN,
                       w4 = SGN, w5 = SGN, w6 = SGN, w7 = SGN;
    {
      const unsigned long long* hp =
          (const unsigned long long*)(hbuf + (t & 3) * (NB * NH) + goff);
      int it = 0;
      while (true) {
        if (w0 & SGN) w0 = AL(hp);
        if (w1 & SGN) w1 = AL(hp + 1);
        if (w2 & SGN) w2 = AL(hp + 8);
        if (w3 & SGN) w3 = AL(hp + 9);
        if (w4 & SGN) w4 = AL(hp + 16);
        if (w5 & SGN) w5 = AL(hp + 17);
        if (w6 & SGN) w6 = AL(hp + 24);
        if (w7 & SGN) w7 = AL(hp + 25);
        unsigned long long s =
            (w0 | w1 | w2 | w3 | w4 | w5 | w6 | w7) & SGN;
        if (__all(s == 0ULL)) break;
        // Geometric backoff: decongest the producers' hot LLC lines so
        // publish stores land instead of losing arbitration to our reads.
        if (it == 0)      __builtin_amdgcn_s_sleep(1);
        else if (it == 1) __builtin_amdgcn_s_sleep(2);
        else if (it == 2) __builtin_amdgcn_s_sleep(4);
        else              __builtin_amdgcn_s_sleep(8);
        ++it;
      }
    }
    union { unsigned long long u[2]; bf16x8 v; } u0, u1, u2, u3;
    u0.u[0] = w0; u0.u[1] = w1; u1.u[0] = w2; u1.u[1] = w3;
    u2.u[0] = w4; u2.u[1] = w5; u3.u[0] = w6; u3.u[1] = w7;
    bf16x8 a0 = u0.v, a1 = u1.v, a2 = u2.v, a3 = u3.v;

    // ---- 32 h-MFMAs ----
    AC00 = MFMA_(a0, BH000, AC00); AC01 = MFMA_(a0, BH010, AC01);
    AC10 = MFMA_(a0, BH100, AC10); AC11 = MFMA_(a0, BH110, AC11);
    AC20 = MFMA_(a0, BH200, AC20); AC21 = MFMA_(a0, BH210, AC21);
    AC30 = MFMA_(a0, BH300, AC30); AC31 = MFMA_(a0, BH310, AC31);
    AC00 = MFMA_(a1, BH001, AC00); AC01 = MFMA_(a1, BH011, AC01);
    AC10 = MFMA_(a1, BH101, AC10); AC11 = MFMA_(a1, BH111, AC11);
    AC20 = MFMA_(a1, BH201, AC20); AC21 = MFMA_(a1, BH211, AC21);
    AC30 = MFMA_(a1, BH301, AC30); AC31 = MFMA_(a1, BH311, AC31);
    AC00 = MFMA_(a2, BH002, AC00); AC01 = MFMA_(a2, BH012, AC01);
    AC10 = MFMA_(a2, BH102, AC10); AC11 = MFMA_(a2, BH112, AC11);
    AC20 = MFMA_(a2, BH202, AC20); AC21 = MFMA_(a2, BH212, AC21);
    AC30 = MFMA_(a2, BH302, AC30); AC31 = MFMA_(a2, BH312, AC31);
    AC00 = MFMA_(a3, BH003, AC00); AC01 = MFMA_(a3, BH013, AC01);
    AC10 = MFMA_(a3, BH103, AC10); AC11 = MFMA_(a3, BH113, AC11);
    AC20 = MFMA_(a3, BH203, AC20); AC21 = MFMA_(a3, BH213, AC21);
    AC30 = MFMA_(a3, BH303, AC30); AC31 = MFMA_(a3, BH313, AC31);

    // ---- Reduction: wave partials -> Gs[t&1] ----
    const int gi = t & 1;
#pragma unroll
    for (int rr = 0; rr < 4; ++rr) {
      int row = q * 4 + rr;
      Gs[gi][wave][row][n16]       = AC00[rr];
      Gs[gi][wave][row][16 + n16]  = AC01[rr];
      Gs[gi][wave][row][32 + n16]  = AC10[rr];
      Gs[gi][wave][row][48 + n16]  = AC11[rr];
      Gs[gi][wave][row][64 + n16]  = AC20[rr];
      Gs[gi][wave][row][80 + n16]  = AC21[rr];
      Gs[gi][wave][row][96 + n16]  = AC30[rr];
      Gs[gi][wave][row][112 + n16] = AC31[rr];
    }

    // S2: the only barrier. Its implicit vmcnt drain also makes last step's
    // publish + re-sentinel stores durable before this step's publish.
    __syncthreads();

    // ---- LSTM cell ----
    {
      float xi = 0.f, xf = 0.f, xg = 0.f, xo = 0.f;
#pragma unroll
      for (int w2i = 0; w2i < 8; ++w2i) {
        xi += Gs[gi][w2i][r_e][c_e];
        xf += Gs[gi][w2i][r_e][32 + c_e];
        xg += Gs[gi][w2i][r_e][64 + c_e];
        xo += Gs[gi][w2i][r_e][96 + c_e];
      }
      float iv = fsigmoid_(xi);
      float fv = fsigmoid_(xf);
      float gv = fsoftplus_(xg);
      float ov = fsigmoid_(xo);
      c_state = fv * c_state + iv * gv;
      float hv = ov * fsoftplus_(c_state);   // hv >= 0 always: sign bit 0
      if (t == NT - 1) {
        hlast[grow * NH + hcol] = hv;
      } else {
        // 8B packed publish into buf (t+1)&3: 2x shfl_xor, lanes c_e%4==0
        float hn1 = __shfl_xor(hv, 1);
        __hip_bfloat162 pk;
        pk.x = (__hip_bfloat16)hv; pk.y = (__hip_bfloat16)hn1;
        unsigned int pw = *(unsigned int*)&pk;
        unsigned int po = (unsigned int)__shfl_xor((int)pw, 2);
        if ((c_e & 3) == 0) {
          unsigned long long vv = ((unsigned long long)po << 32) | pw;
          AS((unsigned long long*)(hbuf + ((t + 1) & 3) * (NB * NH)
                                   + grow * NH + hcol), vv);
          // Re-sentinel my patch of buf (t+3)&3 (held h(t-1), now dead).
          AS((unsigned long long*)(hbuf + ((t + 3) & 3) * (NB * NH)
                                   + grow * NH + hcol),
             0xFFFFFFFFFFFFFFFFULL);
        }
      }
    }

    // ---- Hidden work while the publish round-trips: x-GEMM for t+1 ----
    if (t < NT - 1) XPHASE_(xv)
  }
#undef XFRAG_PTR
#undef XPHASE_
#undef AS
#undef AL
#undef MFMA_
}

// ---------------------------------------------------------------------------
// Kernel 3: projection head. 32 blocks x 128 thr; 4 batch rows per block.
// ---------------------------------------------------------------------------
__global__ __launch_bounds__(128) void proj_kernel(
    const float* __restrict__ hlast,
    const float* __restrict__ Wm, const float* __restrict__ bm,
    const float* __restrict__ Wv, const float* __restrict__ bv,
    const float* __restrict__ eps, float* __restrict__ out) {
  __shared__ float hs[4][NH];
  const int bb = blockIdx.x * 4;
  for (int idx = threadIdx.x; idx < 4 * NH; idx += 128)
    hs[idx >> 10][idx & (NH - 1)] = hlast[(bb + (idx >> 10)) * NH + (idx & (NH - 1))];
  __syncthreads();
  const int z = threadIdx.x;
  float am[4] = {0.f, 0.f, 0.f, 0.f};
  float av[4] = {0.f, 0.f, 0.f, 0.f};
#pragma unroll 8
  for (int k = 0; k < NH; ++k) {
    float wm = Wm[k * NZ + z];
    float wv = Wv[k * NZ + z];
#pragma unroll
    for (int r = 0; r < 4; ++r) {
      am[r] += hs[r][k] * wm;
      av[r] += hs[r][k] * wv;
    }
  }
#pragma unroll
  for (int r = 0; r < 4; ++r) {
    int b = bb + r;
    float mu = am[r] + bm[z];
    float lv = av[r] + bv[z];
    float zz = mu + eps[b * NZ + z] * expf(0.5f * lv);
    out[b * NZ + z] = mu;
    out[NB * NZ + b * NZ + z] = lv;
    out[2 * NB * NZ + b * NZ + z] = zz;
  }
}

// ---------------------------------------------------------------------------
extern "C" void kernel_launch(void* const* d_in, const int* in_sizes, int n_in,
                              void* d_out, int out_size, void* d_ws, size_t ws_size,
                              hipStream_t stream) {
  const float* x   = (const float*)d_in[0];
  const float* W   = (const float*)d_in[1];
  const float* U   = (const float*)d_in[2];
  const float* b   = (const float*)d_in[3];
  const float* Wm  = (const float*)d_in[4];
  const float* bm  = (const float*)d_in[5];
  const float* Wv  = (const float*)d_in[6];
  const float* bv  = (const float*)d_in[7];
  const float* eps = (const float*)d_in[8];

  // Workspace layout:
  //   [0,       1048576)   hbuf: 4-deep ring of B x H bf16 (256KB each)
  //   [1048576, +33.5MB)   xb: T x B x D bf16
  //   hlast (B x H fp32, 512KB) ALIASES xb's t<8 region: x(t<8) is dead
  //   after step 7; hlast is written only at step NT-1.
  char* ws = (char*)d_ws;
  __bf16* hbuf = (__bf16*)ws;
  __bf16* xb   = (__bf16*)(ws + 1048576);
  float* hlast = (float*)(ws + 1048576);

  // buf0 = h(0) = 0 (sign-clear = "present"); bufs 1..3 = 0xFFFF sentinel.
  hipMemsetAsync(hbuf, 0, NB * NH * sizeof(__bf16), stream);
  hipMemsetAsync(hbuf + NB * NH, 0xFF, 3 * NB * NH * sizeof(__bf16), stream);

  convert_x_kernel<<<dim3((NB * NT * ND) / 4 / 256), dim3(256), 0, stream>>>(
      (const float4*)x, xb);

  void* args[] = {(void*)&xb, (void*)&W, (void*)&U, (void*)&b,
                  (void*)&hbuf, (void*)&hlast};
  hipLaunchCooperativeKernel(reinterpret_cast<void*>(lstm_persistent),
                             dim3(256), dim3(512), args, 0, stream);

  proj_kernel<<<dim3(32), dim3(128), 0, stream>>>(hlast, Wm, bm, Wv, bv, eps,
                                                  (float*)d_out);
}